// Round 5
// baseline (126.982 us; speedup 1.0000x reference)
//
#include <hip/hip_runtime.h>

// T=2^21 sequential nonlinear storage recurrence + per-column z-score.
// Chunked scan with redundant warm-up (W=512, L=64). R5: per-element work
// (pn/en, tanh, col0-3 stats) hoisted into a coalesced LDS staging phase;
// the 576-step serial loop consumes precomputed fp32 (tp,te) from padded LDS
// (+1/row -> 2-way bank = free) via 8-step-lead double-buffered named regs.
// Loop body is ~28 FMA + 2 ds_read per step.

#define T_TOTAL  (1 << 21)
#define L_CHUNK  64
#define W_WARM   512
#define STEPS    (W_WARM + L_CHUNK)          // 576
#define C_CHUNKS (T_TOTAL / L_CHUNK)         // 32768
#define N_BLOCKS (C_CHUNKS / 64)             // 512 blocks, 1 wave each
#define SPAN     (64 * L_CHUNK + W_WARM)     // 4608 elements per block
#define NSEG     (SPAN / 128)                // 36 float4 loads per lane
#define LDSN     4704                        // padded: max p = 4687
#define SIDE_OFF 1024

// one recurrence step consuming precomputed tp=tanh(pn/x1), te=tanh(en/x1)
#define PSTEP(TP, TE, PS, PC)                                              \
    {                                                                      \
        float r   = s * inv_x1;                                            \
        float e1  = r * (TP);                                              \
        float q1  = (1.0f - e1) * fmaf(e1, e1, 1.0f);   /* ~1/(1+e1) */    \
        float Av  = (x1s * (TP)) * fmaf(-r, r, 1.0f);                      \
        float p_s = Av * q1;                                               \
        float omr = 1.0f - r;                                              \
        float e2  = (TE) * omr;                                            \
        float q2  = (1.0f - e2) * fmaf(e2, e2, 1.0f);   /* ~1/(1+e2) */    \
        float Bv  = (s * (2.0f - r)) * (TE);                               \
        float e_s = Bv * q2;                                               \
        float s1  = s + (p_s - e_s);                                       \
        float y   = s1 * c449;                                             \
        float y2  = y * y;                                                 \
        float u   = y2 * y2;                                               \
        float pl  = fmaf(u, fmaf(u, 0.1171875f, -0.15625f), 0.25f);        \
        PC = (s1 * u) * pl;          /* s1*(1-(1+u)^-1/4) */               \
        PS = p_s;                                                          \
        s  = s1 - PC;                                                      \
    }

// load 8 (tp,te) pairs for steps JJ..JJ+7 (addresses linear: no row cross)
#define LOAD8(T0_,T1_,T2_,T3_,T4_,T5_,T6_,T7_,E0_,E1_,E2_,E3_,E4_,E5_,E6_,E7_,JJ) \
    {                                                                      \
        int mm = lane64 + (JJ);                                            \
        const float* pt = lds + (mm + (mm >> 6));                          \
        T0_ = pt[0]; T1_ = pt[1]; T2_ = pt[2]; T3_ = pt[3];                \
        T4_ = pt[4]; T5_ = pt[5]; T6_ = pt[6]; T7_ = pt[7];                \
        E0_ = pt[LDSN + 0]; E1_ = pt[LDSN + 1]; E2_ = pt[LDSN + 2];        \
        E3_ = pt[LDSN + 3]; E4_ = pt[LDSN + 4]; E5_ = pt[LDSN + 5];        \
        E6_ = pt[LDSN + 6]; E7_ = pt[LDSN + 7];                            \
    }

// consume 8 steps; emit (stores+stats) only when J0V >= W_WARM (uniform)
#define CONS8(T0_,T1_,T2_,T3_,T4_,T5_,T6_,T7_,E0_,E1_,E2_,E3_,E4_,E5_,E6_,E7_,J0V) \
    {                                                                      \
        float ps0,pc0,ps1,pc1,ps2,pc2,ps3,pc3;                             \
        float ps4,pc4,ps5,pc5,ps6,pc6,ps7,pc7;                             \
        PSTEP(T0_,E0_,ps0,pc0) PSTEP(T1_,E1_,ps1,pc1)                      \
        PSTEP(T2_,E2_,ps2,pc2) PSTEP(T3_,E3_,ps3,pc3)                      \
        PSTEP(T4_,E4_,ps4,pc4) PSTEP(T5_,E5_,ps5,pc5)                      \
        PSTEP(T6_,E6_,ps6,pc6) PSTEP(T7_,E7_,ps7,pc7)                      \
        if ((J0V) >= W_WARM) {                                             \
            size_t tb = (size_t)t_base + (size_t)((J0V) - W_WARM);         \
            if (SIDE) {                                                    \
                float4* sp = (float4*)(side + 2 * tb);                     \
                sp[0] = make_float4(ps0, pc0, ps1, pc1);                   \
                sp[1] = make_float4(ps2, pc2, ps3, pc3);                   \
                sp[2] = make_float4(ps4, pc4, ps5, pc5);                   \
                sp[3] = make_float4(ps6, pc6, ps7, pc7);                   \
            } else {                                                       \
                float* op = out + 6 * tb + 4;                              \
                *(float2*)(op +  0) = make_float2(ps0, pc0);               \
                *(float2*)(op +  6) = make_float2(ps1, pc1);               \
                *(float2*)(op + 12) = make_float2(ps2, pc2);               \
                *(float2*)(op + 18) = make_float2(ps3, pc3);               \
                *(float2*)(op + 24) = make_float2(ps4, pc4);               \
                *(float2*)(op + 30) = make_float2(ps5, pc5);               \
                *(float2*)(op + 36) = make_float2(ps6, pc6);               \
                *(float2*)(op + 42) = make_float2(ps7, pc7);               \
            }                                                              \
            sum4 += ps0; sq4 = fmaf(ps0, ps0, sq4);                        \
            sum4 += ps1; sq4 = fmaf(ps1, ps1, sq4);                        \
            sum4 += ps2; sq4 = fmaf(ps2, ps2, sq4);                        \
            sum4 += ps3; sq4 = fmaf(ps3, ps3, sq4);                        \
            sum4 += ps4; sq4 = fmaf(ps4, ps4, sq4);                        \
            sum4 += ps5; sq4 = fmaf(ps5, ps5, sq4);                        \
            sum4 += ps6; sq4 = fmaf(ps6, ps6, sq4);                        \
            sum4 += ps7; sq4 = fmaf(ps7, ps7, sq4);                        \
            sum5 += pc0; sq5 = fmaf(pc0, pc0, sq5);                        \
            sum5 += pc1; sq5 = fmaf(pc1, pc1, sq5);                        \
            sum5 += pc2; sq5 = fmaf(pc2, pc2, sq5);                        \
            sum5 += pc3; sq5 = fmaf(pc3, pc3, sq5);                        \
            sum5 += pc4; sq5 = fmaf(pc4, pc4, sq5);                        \
            sum5 += pc5; sq5 = fmaf(pc5, pc5, sq5);                        \
            sum5 += pc6; sq5 = fmaf(pc6, pc6, sq5);                        \
            sum5 += pc7; sq5 = fmaf(pc7, pc7, sq5);                        \
        }                                                                  \
    }

template <bool SIDE>
__global__ __launch_bounds__(64, 1) void scan_kernel(const float4* __restrict__ x4,
                                                     const float* __restrict__ x1p,
                                                     float* __restrict__ out,
                                                     float* __restrict__ side,
                                                     double* __restrict__ stats) {
    __shared__ float lds[2 * LDSN];    // [0]=tp array, [LDSN]=te array, +1/64 pad

    const float x1s    = x1p[0];
    const float inv_x1 = 1.0f / x1s;
    const float c449   = (4.0f / 9.0f) * inv_x1;

    const int lane   = threadIdx.x;
    const int lane64 = lane * 64;
    const int t_base = blockIdx.x * (64 * L_CHUNK) + lane * L_CHUNK; // chunk start t

    float sum0 = 0, sum1 = 0, sum2 = 0, sum3 = 0, sum4 = 0, sum5 = 0;
    float sq0 = 0, sq1 = 0, sq2 = 0, sq3 = 0, sq4 = 0, sq5 = 0;

    // ---- staging: coalesced loads, per-element precompute, col0-3 stats ----
    const int g4base = blockIdx.x * (SPAN / 2 - W_WARM / 2) - W_WARM / 2 + lane;
    // = blockIdx*2048 - 256 + lane ; float4 index of elements {2q,2q+1}
#pragma unroll 4
    for (int seg = 0; seg < NSEG; ++seg) {
        int q  = seg * 64 + lane;                 // element-pair index in span
        int g4 = blockIdx.x * 2048 - 256 + q;     // global float4 index
        float4 v = x4[max(g4, 0)];
        float pn0 = fmaxf(v.x - v.y, 0.0f), en0 = fmaxf(v.y - v.x, 0.0f);
        float pn1 = fmaxf(v.z - v.w, 0.0f), en1 = fmaxf(v.w - v.z, 0.0f);
        if (g4 < 0) { pn0 = en0 = pn1 = en1 = 0.0f; }   // t<0: identity steps
        float a0 = pn0 * inv_x1, b0 = en0 * inv_x1;
        float a1 = pn1 * inv_x1, b1 = en1 * inv_x1;
        float tp0 = a0 * fmaf(a0 * a0, -0.33333334f, 1.0f);
        float te0 = b0 * fmaf(b0 * b0, -0.33333334f, 1.0f);
        float tp1 = a1 * fmaf(a1 * a1, -0.33333334f, 1.0f);
        float te1 = b1 * fmaf(b1 * b1, -0.33333334f, 1.0f);
        int m = 2 * q;
        int p = m + (m >> 6);                     // +1-per-64 pad; m even -> p,p+1 same row
        lds[p]            = tp0; lds[p + 1]        = tp1;
        lds[LDSN + p]     = te0; lds[LDSN + p + 1] = te1;
        if (seg >= 4) {                           // emit region only (m>=512), exact once
            sum0 += v.x; sq0 = fmaf(v.x, v.x, sq0);
            sum0 += v.z; sq0 = fmaf(v.z, v.z, sq0);
            sum1 += v.y; sq1 = fmaf(v.y, v.y, sq1);
            sum1 += v.w; sq1 = fmaf(v.w, v.w, sq1);
            sum2 += pn0; sq2 = fmaf(pn0, pn0, sq2);
            sum2 += pn1; sq2 = fmaf(pn1, pn1, sq2);
            sum3 += en0; sq3 = fmaf(en0, en0, sq3);
            sum3 += en1; sq3 = fmaf(en1, en1, sq3);
        }
    }
    __syncthreads();

    // ---- serial scan: 576 steps, double-buffered 8-step groups ----
    float s = 0.0f;
    float tA0,tA1,tA2,tA3,tA4,tA5,tA6,tA7, eA0,eA1,eA2,eA3,eA4,eA5,eA6,eA7;
    float tB0,tB1,tB2,tB3,tB4,tB5,tB6,tB7, eB0,eB1,eB2,eB3,eB4,eB5,eB6,eB7;

    LOAD8(tA0,tA1,tA2,tA3,tA4,tA5,tA6,tA7,eA0,eA1,eA2,eA3,eA4,eA5,eA6,eA7, 0)
#pragma unroll 1
    for (int j0 = 0; j0 < STEPS; j0 += 16) {
        LOAD8(tB0,tB1,tB2,tB3,tB4,tB5,tB6,tB7,eB0,eB1,eB2,eB3,eB4,eB5,eB6,eB7, j0 + 8)
        CONS8(tA0,tA1,tA2,tA3,tA4,tA5,tA6,tA7,eA0,eA1,eA2,eA3,eA4,eA5,eA6,eA7, j0)
        LOAD8(tA0,tA1,tA2,tA3,tA4,tA5,tA6,tA7,eA0,eA1,eA2,eA3,eA4,eA5,eA6,eA7, j0 + 16)
        CONS8(tB0,tB1,tB2,tB3,tB4,tB5,tB6,tB7,eB0,eB1,eB2,eB3,eB4,eB5,eB6,eB7, j0 + 8)
    }

    double v[12] = {sum0, sum1, sum2, sum3, sum4, sum5,
                    sq0, sq1, sq2, sq3, sq4, sq5};
#pragma unroll
    for (int c = 0; c < 12; ++c) {
        double val = v[c];
        for (int off = 32; off > 0; off >>= 1)
            val += __shfl_down(val, off, 64);
        if (threadIdx.x == 0) atomicAdd(&stats[c], val);
    }
}

__global__ void finalize_stats(const double* __restrict__ stats,
                               float* __restrict__ musig) {
    int c = threadIdx.x;
    if (c < 6) {
        double sum = stats[c], sumsq = stats[6 + c];
        double n = (double)T_TOTAL;
        double mu = sum / n;
        double var = (sumsq - sum * sum / n) / (n - 1.0);
        double sig = sqrt(var);
        musig[c] = (float)mu;
        musig[6 + c] = (float)(1.0 / sig);
    }
}

template <bool SIDE>
__global__ __launch_bounds__(256) void normalize_kernel(const float4* __restrict__ xp4,
                                                        const float4* __restrict__ side4,
                                                        float* __restrict__ out,
                                                        const float* __restrict__ musig) {
    float mu[6], is[6];
#pragma unroll
    for (int c = 0; c < 6; ++c) { mu[c] = musig[c]; is[c] = musig[6 + c]; }

    int idx = blockIdx.x * blockDim.x + threadIdx.x;
    int stride = gridDim.x * blockDim.x;
    for (int p = idx; p < T_TOTAL / 2; p += stride) {
        float4 xv = xp4[p];                         // rows 2p, 2p+1
        float* o = out + 12 * (size_t)p;
        float4 sv;
        if (SIDE) {
            sv = side4[p];                          // {ps0,pc0,ps1,pc1}
        } else {
            float2 a = *(const float2*)(o + 4);
            float2 b = *(const float2*)(o + 10);
            sv = make_float4(a.x, a.y, b.x, b.y);
        }
        float pn0 = fmaxf(xv.x - xv.y, 0.0f), en0 = fmaxf(xv.y - xv.x, 0.0f);
        float pn1 = fmaxf(xv.z - xv.w, 0.0f), en1 = fmaxf(xv.w - xv.z, 0.0f);
        float4 o0 = {(xv.x - mu[0]) * is[0], (xv.y - mu[1]) * is[1],
                     (pn0 - mu[2]) * is[2], (en0 - mu[3]) * is[3]};
        float4 o1 = {(sv.x - mu[4]) * is[4], (sv.y - mu[5]) * is[5],
                     (xv.z - mu[0]) * is[0], (xv.w - mu[1]) * is[1]};
        float4 o2 = {(pn1 - mu[2]) * is[2], (en1 - mu[3]) * is[3],
                     (sv.z - mu[4]) * is[4], (sv.w - mu[5]) * is[5]};
        *(float4*)(o + 0) = o0;
        *(float4*)(o + 4) = o1;
        *(float4*)(o + 8) = o2;
    }
}

extern "C" void kernel_launch(void* const* d_in, const int* in_sizes, int n_in,
                              void* d_out, int out_size, void* d_ws, size_t ws_size,
                              hipStream_t stream) {
    const float4* x4 = (const float4*)d_in[0];
    const float* x1 = (const float*)d_in[1];
    float* out = (float*)d_out;
    double* stats = (double*)d_ws;
    float* musig = (float*)((char*)d_ws + 12 * sizeof(double));
    float* side  = (float*)((char*)d_ws + SIDE_OFF);

    const bool use_side = ws_size >= (size_t)SIDE_OFF + (size_t)T_TOTAL * 8;

    hipMemsetAsync(d_ws, 0, 12 * sizeof(double), stream);
    if (use_side) {
        scan_kernel<true><<<N_BLOCKS, 64, 0, stream>>>(x4, x1, out, side, stats);
        finalize_stats<<<1, 64, 0, stream>>>(stats, musig);
        normalize_kernel<true><<<2048, 256, 0, stream>>>(x4, (const float4*)side,
                                                         out, musig);
    } else {
        scan_kernel<false><<<N_BLOCKS, 64, 0, stream>>>(x4, x1, out, side, stats);
        finalize_stats<<<1, 64, 0, stream>>>(stats, musig);
        normalize_kernel<false><<<2048, 256, 0, stream>>>(x4, (const float4*)side,
                                                          out, musig);
    }
}

// Round 6
// 108.692 us; speedup vs baseline: 1.1683x; 1.1683x over previous
//
#include <hip/hip_runtime.h>

// T=2^21 sequential nonlinear storage recurrence + per-column z-score.
// Chunked scan with redundant warm-up (W=512). R6: across R1-R5 the serial
// loop's wall is ~300-420cy/step vs ~110-150cy issue, regardless of feed
// structure -> solo-wave issue cadence/latency is the stall; every prior
// round ran <=1 wave/SIMD. Fix: L=16 -> 131072 chunks -> 2048 waves, launched
// as 512 x 256-thread blocks = 8 waves/CU = 2 waves/SIMD co-resident.
// Feed: R4-style global float4 ring (8 named bufs, 16-step lead).

#define T_TOTAL  (1 << 21)
#define L_CHUNK  16
#define W_WARM   512
#define STEPS    (W_WARM + L_CHUNK)          // 528
#define C_CHUNKS (T_TOTAL / L_CHUNK)         // 131072
#define THREADS  256
#define N_BLOCKS (C_CHUNKS / THREADS)        // 512 blocks -> 2 blocks/CU
#define SIDE_OFF 1024

// one recurrence step, pure FMA (polys for 1/(1+eps) and (1+u)^-1/4)
#define PSTEP(TP, TE, PS, PC)                                              \
    {                                                                      \
        float r   = s * inv_x1;                                            \
        float e1  = r * (TP);                                              \
        float q1  = (1.0f - e1) * fmaf(e1, e1, 1.0f);   /* ~1/(1+e1) */    \
        float Av  = (x1s * (TP)) * fmaf(-r, r, 1.0f);                      \
        float p_s = Av * q1;                                               \
        float omr = 1.0f - r;                                              \
        float e2  = (TE) * omr;                                            \
        float q2  = (1.0f - e2) * fmaf(e2, e2, 1.0f);   /* ~1/(1+e2) */    \
        float Bv  = (s * (2.0f - r)) * (TE);                               \
        float e_s = Bv * q2;                                               \
        float s1  = s + (p_s - e_s);                                       \
        float y   = s1 * c449;                                             \
        float y2  = y * y;                                                 \
        float u   = y2 * y2;                                               \
        float pl  = fmaf(u, fmaf(u, 0.1171875f, -0.15625f), 0.25f);        \
        PC = (s1 * u) * pl;          /* s1*(1-(1+u)^-1/4) */               \
        PS = p_s;                                                          \
        s  = s1 - PC;                                                      \
    }

// raw step from input pair (dx,dy): derive pn/en/tanh then PSTEP
#define STEP(dx, dy, MASK, tcur, PS, PC)                                   \
    {                                                                      \
        float pn = fmaxf((dx) - (dy), 0.0f);                               \
        float en = fmaxf((dy) - (dx), 0.0f);                               \
        if (MASK) { if ((tcur) < 0) { pn = 0.0f; en = 0.0f; } }            \
        float xpn = pn * inv_x1, xen = en * inv_x1;                        \
        float tp  = xpn * fmaf(xpn * xpn, -0.33333334f, 1.0f);             \
        float te  = xen * fmaf(xen * xen, -0.33333334f, 1.0f);             \
        PSTEP(tp, te, PS, PC)                                              \
    }

#define ACCUM(dx, dy, p_s, perc)                                           \
    {                                                                      \
        float pn = fmaxf((dx) - (dy), 0.0f);                               \
        float en = fmaxf((dy) - (dx), 0.0f);                               \
        sum0 += (dx);  sq0 = fmaf((dx), (dx), sq0);                        \
        sum1 += (dy);  sq1 = fmaf((dy), (dy), sq1);                        \
        sum2 += pn;    sq2 = fmaf(pn, pn, sq2);                            \
        sum3 += en;    sq3 = fmaf(en, en, sq3);                            \
        sum4 += p_s;   sq4 = fmaf(p_s, p_s, sq4);                          \
        sum5 += perc;  sq5 = fmaf(perc, perc, sq5);                        \
    }

// two steps from one float4 buf; reload buf 16 steps ahead; optional emit
#define PAIR(BUF, EMIT, MASK, tp2)                                         \
    {                                                                      \
        float ps0, pc0, ps1, pc1;                                          \
        STEP(BUF.x, BUF.y, MASK, (tp2) + 0, ps0, pc0)                      \
        STEP(BUF.z, BUF.w, MASK, (tp2) + 1, ps1, pc1)                      \
        float4 dsave = BUF;                                                \
        BUF = ld4((tp2) + 16);                                             \
        if (EMIT) {                                                        \
            if (SIDE) {                                                    \
                *(float4*)(side + 2 * (size_t)(tp2)) =                     \
                    make_float4(ps0, pc0, ps1, pc1);                       \
            } else {                                                       \
                *(float2*)(out + 6 * (size_t)(tp2) + 4)  = make_float2(ps0, pc0); \
                *(float2*)(out + 6 * (size_t)(tp2) + 10) = make_float2(ps1, pc1); \
            }                                                              \
            ACCUM(dsave.x, dsave.y, ps0, pc0)                              \
            ACCUM(dsave.z, dsave.w, ps1, pc1)                              \
        }                                                                  \
    }

#define GROUP(EMIT, MASK, tg)                                              \
    {                                                                      \
        PAIR(bufA, EMIT, MASK, (tg) + 0)                                   \
        PAIR(bufB, EMIT, MASK, (tg) + 2)                                   \
        PAIR(bufC, EMIT, MASK, (tg) + 4)                                   \
        PAIR(bufD, EMIT, MASK, (tg) + 6)                                   \
        PAIR(bufE, EMIT, MASK, (tg) + 8)                                   \
        PAIR(bufF, EMIT, MASK, (tg) + 10)                                  \
        PAIR(bufG, EMIT, MASK, (tg) + 12)                                  \
        PAIR(bufH, EMIT, MASK, (tg) + 14)                                  \
    }

template <bool SIDE>
__global__ __launch_bounds__(THREADS, 2) void scan_kernel(const float4* __restrict__ xp4,
                                                          const float* __restrict__ x1p,
                                                          float* __restrict__ out,
                                                          float* __restrict__ side,
                                                          double* __restrict__ stats) {
    const float x1s    = x1p[0];
    const float inv_x1 = 1.0f / x1s;
    const float c449   = (4.0f / 9.0f) * inv_x1;

    const int k  = blockIdx.x * THREADS + threadIdx.x;  // chunk id
    const int t0 = k * L_CHUNK - W_WARM;                // even

    auto ld4 = [&](int tt) -> float4 {
        int tc = min(max(tt, 0), T_TOTAL - 2);          // tt even -> tc even
        return xp4[tc >> 1];
    };

    float4 bufA = ld4(t0 + 0),  bufB = ld4(t0 + 2);
    float4 bufC = ld4(t0 + 4),  bufD = ld4(t0 + 6);
    float4 bufE = ld4(t0 + 8),  bufF = ld4(t0 + 10);
    float4 bufG = ld4(t0 + 12), bufH = ld4(t0 + 14);

    float s = 0.0f;
    float sum0 = 0, sum1 = 0, sum2 = 0, sum3 = 0, sum4 = 0, sum5 = 0;
    float sq0 = 0, sq1 = 0, sq2 = 0, sq3 = 0, sq4 = 0, sq5 = 0;

#pragma unroll 1
    for (int j0 = 0; j0 < W_WARM; j0 += 16) {           // warm: no emit
        const int tg = t0 + j0;
        GROUP(false, true, tg)
    }
    {                                                   // emit: exactly L=16 steps
        const int tg = t0 + W_WARM;                     // = k*L_CHUNK >= 0
        GROUP(true, false, tg)
    }

    // block-level reduction: wave shuffle -> LDS -> single atomic per channel
    __shared__ double red[4][12];
    double v[12] = {sum0, sum1, sum2, sum3, sum4, sum5,
                    sq0, sq1, sq2, sq3, sq4, sq5};
    const int wid  = threadIdx.x >> 6;
    const int lane = threadIdx.x & 63;
#pragma unroll
    for (int c = 0; c < 12; ++c) {
        double val = v[c];
        for (int off = 32; off > 0; off >>= 1)
            val += __shfl_down(val, off, 64);
        if (lane == 0) red[wid][c] = val;
    }
    __syncthreads();
    if (threadIdx.x < 12) {
        int c = threadIdx.x;
        double tot = red[0][c] + red[1][c] + red[2][c] + red[3][c];
        atomicAdd(&stats[c], tot);
    }
}

__global__ void finalize_stats(const double* __restrict__ stats,
                               float* __restrict__ musig) {
    int c = threadIdx.x;
    if (c < 6) {
        double sum = stats[c], sumsq = stats[6 + c];
        double n = (double)T_TOTAL;
        double mu = sum / n;
        double var = (sumsq - sum * sum / n) / (n - 1.0);
        double sig = sqrt(var);
        musig[c] = (float)mu;
        musig[6 + c] = (float)(1.0 / sig);
    }
}

template <bool SIDE>
__global__ __launch_bounds__(256) void normalize_kernel(const float4* __restrict__ xp4,
                                                        const float4* __restrict__ side4,
                                                        float* __restrict__ out,
                                                        const float* __restrict__ musig) {
    float mu[6], is[6];
#pragma unroll
    for (int c = 0; c < 6; ++c) { mu[c] = musig[c]; is[c] = musig[6 + c]; }

    int idx = blockIdx.x * blockDim.x + threadIdx.x;
    int stride = gridDim.x * blockDim.x;
    for (int p = idx; p < T_TOTAL / 2; p += stride) {
        float4 xv = xp4[p];                         // rows 2p, 2p+1
        float* o = out + 12 * (size_t)p;
        float4 sv;
        if (SIDE) {
            sv = side4[p];                          // {ps0,pc0,ps1,pc1}
        } else {
            float2 a = *(const float2*)(o + 4);
            float2 b = *(const float2*)(o + 10);
            sv = make_float4(a.x, a.y, b.x, b.y);
        }
        float pn0 = fmaxf(xv.x - xv.y, 0.0f), en0 = fmaxf(xv.y - xv.x, 0.0f);
        float pn1 = fmaxf(xv.z - xv.w, 0.0f), en1 = fmaxf(xv.w - xv.z, 0.0f);
        float4 o0 = {(xv.x - mu[0]) * is[0], (xv.y - mu[1]) * is[1],
                     (pn0 - mu[2]) * is[2], (en0 - mu[3]) * is[3]};
        float4 o1 = {(sv.x - mu[4]) * is[4], (sv.y - mu[5]) * is[5],
                     (xv.z - mu[0]) * is[0], (xv.w - mu[1]) * is[1]};
        float4 o2 = {(pn1 - mu[2]) * is[2], (en1 - mu[3]) * is[3],
                     (sv.z - mu[4]) * is[4], (sv.w - mu[5]) * is[5]};
        *(float4*)(o + 0) = o0;
        *(float4*)(o + 4) = o1;
        *(float4*)(o + 8) = o2;
    }
}

extern "C" void kernel_launch(void* const* d_in, const int* in_sizes, int n_in,
                              void* d_out, int out_size, void* d_ws, size_t ws_size,
                              hipStream_t stream) {
    const float4* x4 = (const float4*)d_in[0];
    const float* x1 = (const float*)d_in[1];
    float* out = (float*)d_out;
    double* stats = (double*)d_ws;
    float* musig = (float*)((char*)d_ws + 12 * sizeof(double));
    float* side  = (float*)((char*)d_ws + SIDE_OFF);

    const bool use_side = ws_size >= (size_t)SIDE_OFF + (size_t)T_TOTAL * 8;

    hipMemsetAsync(d_ws, 0, 12 * sizeof(double), stream);
    if (use_side) {
        scan_kernel<true><<<N_BLOCKS, THREADS, 0, stream>>>(x4, x1, out, side, stats);
        finalize_stats<<<1, 64, 0, stream>>>(stats, musig);
        normalize_kernel<true><<<2048, 256, 0, stream>>>(x4, (const float4*)side,
                                                         out, musig);
    } else {
        scan_kernel<false><<<N_BLOCKS, THREADS, 0, stream>>>(x4, x1, out, side, stats);
        finalize_stats<<<1, 64, 0, stream>>>(stats, musig);
        normalize_kernel<false><<<2048, 256, 0, stream>>>(x4, (const float4*)side,
                                                          out, musig);
    }
}

// Round 9
// 78.572 us; speedup vs baseline: 1.6161x; 1.3833x over previous
//
#include <hip/hip_runtime.h>

// T=2^21 sequential nonlinear storage recurrence + per-column z-score.
// R9: prepass computes per-16-row window stats {A=x1*Sum tp, Q=x1*Sum tp^2,
// Te, Qe}; warm-up = 40 COARSE windows via clamped Heun/RK2 on the averaged
// drift (s clamped to [0,320] -> polys stay in domain, NaN-impossible)
// + 192 EXACT fine steps + 16 exact emit. R8 (tail=64) hit absmax 0.219 vs
// thr 0.175; tail=192 damps the coarse handoff bias by a further lambda^128
// (~0.2-0.4) -> predicted 0.05-0.10.

#define T_TOTAL   (1 << 21)
#define L_CHUNK   16
#define C_CHUNKS  (T_TOTAL / L_CHUNK)        // 131072 chunks == windows
#define NCOARSE   40
#define NTAIL     192                        // exact fine steps before emit
#define WPAD      52                         // (NCOARSE*16 + NTAIL)/16
#define THREADS   256
#define NBLOCKS   (C_CHUNKS / THREADS)       // 512

// ws layout (bytes)
#define OFF_STATS 0                                   // 12 double
#define OFF_MUSIG 96                                  // 12 float
#define OFF_S4    4096                                // (WPAD+C) float4
#define OFF_SIDE  (OFF_S4 + (WPAD + C_CHUNKS) * 16)   // T float2 (ps,perc)

// ---------------- pre-pass: per-window sufficient statistics ----------------
__global__ __launch_bounds__(256, 2) void prepass_kernel(const float4* __restrict__ x4,
                                                         const float* __restrict__ x1p,
                                                         float4* __restrict__ s4,
                                                         double* __restrict__ stats) {
    const float x1s    = x1p[0];
    const float inv_x1 = 1.0f / x1s;
    const int w = blockIdx.x * 256 + threadIdx.x;     // window id
    const float4* px = x4 + 8 * (size_t)w;

    float Tp = 0, Qp = 0, Te = 0, Qe = 0;
    float s0 = 0, s1 = 0, s2c = 0, s3 = 0, q0 = 0, q1 = 0, q2 = 0, q3 = 0;
#pragma unroll
    for (int q = 0; q < 8; ++q) {
        float4 v = px[q];
        float pn0 = fmaxf(v.x - v.y, 0.0f), en0 = fmaxf(v.y - v.x, 0.0f);
        float pn1 = fmaxf(v.z - v.w, 0.0f), en1 = fmaxf(v.w - v.z, 0.0f);
        float a0 = pn0 * inv_x1, b0 = en0 * inv_x1;
        float a1 = pn1 * inv_x1, b1 = en1 * inv_x1;
        float tp0 = a0 * fmaf(a0 * a0, -0.33333334f, 1.0f);
        float te0 = b0 * fmaf(b0 * b0, -0.33333334f, 1.0f);
        float tp1 = a1 * fmaf(a1 * a1, -0.33333334f, 1.0f);
        float te1 = b1 * fmaf(b1 * b1, -0.33333334f, 1.0f);
        Tp += tp0 + tp1;  Te += te0 + te1;
        Qp = fmaf(tp0, tp0, Qp); Qp = fmaf(tp1, tp1, Qp);
        Qe = fmaf(te0, te0, Qe); Qe = fmaf(te1, te1, Qe);
        s0 += v.x + v.z; q0 = fmaf(v.x, v.x, q0); q0 = fmaf(v.z, v.z, q0);
        s1 += v.y + v.w; q1 = fmaf(v.y, v.y, q1); q1 = fmaf(v.w, v.w, q1);
        s2c += pn0 + pn1; q2 = fmaf(pn0, pn0, q2); q2 = fmaf(pn1, pn1, q2);
        s3 += en0 + en1; q3 = fmaf(en0, en0, q3); q3 = fmaf(en1, en1, q3);
    }
    s4[WPAD + w] = make_float4(x1s * Tp, x1s * Qp, Te, Qe);
    if (blockIdx.x == 0 && threadIdx.x < WPAD)         // zero pads (t<0)
        s4[threadIdx.x] = make_float4(0, 0, 0, 0);

    __shared__ double red[4][8];
    double vv[8] = {s0, s1, s2c, s3, q0, q1, q2, q3};
    const int wid = threadIdx.x >> 6, lane = threadIdx.x & 63;
#pragma unroll
    for (int c = 0; c < 8; ++c) {
        double val = vv[c];
        for (int off = 32; off > 0; off >>= 1) val += __shfl_down(val, off, 64);
        if (lane == 0) red[wid][c] = val;
    }
    __syncthreads();
    if (threadIdx.x < 8) {
        int c = threadIdx.x;
        double tot = red[0][c] + red[1][c] + red[2][c] + red[3][c];
        atomicAdd(&stats[c < 4 ? c : c + 2], tot);     // sums 0-3, sq 6-9
    }
}

// ---------------- scan kernel ----------------
#define CL(v) fminf(fmaxf((v), 0.0f), 320.0f)

// window-averaged drift at state SV using stats C = {A, Q, Te, Qe}
#define DRIFT(SV, C, OUT)                                                  \
    {                                                                      \
        float r_  = (SV) * inv_x1;                                         \
        float P_  = fmaf(-r_, r_, 1.0f) * fmaf(-r_, (C).y, (C).x);         \
        float E_  = ((SV) * (2.0f - r_)) * fmaf(-(1.0f - r_), (C).w, (C).z); \
        float y_  = (SV) * c449;                                           \
        float y2_ = y_ * y_;                                               \
        float u_  = y2_ * y2_;                                             \
        float pl_ = fmaf(u_, fmaf(u_, 1.875f, -2.5f), 4.0f);  /* 16x */    \
        OUT = P_ - E_ - ((SV) * u_) * pl_;                                 \
    }

// one coarse window: clamped Heun (RK2)
#define CSTEP(C)                                                           \
    {                                                                      \
        float k1_, k2_;                                                    \
        DRIFT(s, C, k1_)                                                   \
        float sm_ = CL(s + k1_);                                           \
        DRIFT(sm_, C, k2_)                                                 \
        s = CL(fmaf(0.5f, k1_ + k2_, s));                                  \
    }

#define CGRP_R(OFF)                                                        \
    CSTEP(c0) c0 = ps4[(OFF) + 8];  CSTEP(c1) c1 = ps4[(OFF) + 9];         \
    CSTEP(c2) c2 = ps4[(OFF) + 10]; CSTEP(c3) c3 = ps4[(OFF) + 11];        \
    CSTEP(c4) c4 = ps4[(OFF) + 12]; CSTEP(c5) c5 = ps4[(OFF) + 13];        \
    CSTEP(c6) c6 = ps4[(OFF) + 14]; CSTEP(c7) c7 = ps4[(OFF) + 15];
#define CGRP_L                                                             \
    CSTEP(c0) CSTEP(c1) CSTEP(c2) CSTEP(c3)                                \
    CSTEP(c4) CSTEP(c5) CSTEP(c6) CSTEP(c7)

// one exact fine step, state-update only (masked for t<0)
#define FSTEP(dx, dy, TT)                                                  \
    {                                                                      \
        float pn = fmaxf((dx) - (dy), 0.0f);                               \
        float en = fmaxf((dy) - (dx), 0.0f);                               \
        if ((TT) < 0) { pn = 0.0f; en = 0.0f; }                            \
        float xpn = pn * inv_x1, xen = en * inv_x1;                        \
        float tp  = xpn * fmaf(xpn * xpn, -0.33333334f, 1.0f);             \
        float te  = xen * fmaf(xen * xen, -0.33333334f, 1.0f);             \
        float r   = s * inv_x1;                                            \
        float e1  = r * tp;                                                \
        float q1v = (1.0f - e1) * fmaf(e1, e1, 1.0f);                      \
        float Av  = (x1s * tp) * fmaf(-r, r, 1.0f);                        \
        float p_s = Av * q1v;                                              \
        float omr = 1.0f - r;                                              \
        float e2  = te * omr;                                              \
        float q2v = (1.0f - e2) * fmaf(e2, e2, 1.0f);                      \
        float Bv  = (s * (2.0f - r)) * te;                                 \
        float e_s = Bv * q2v;                                              \
        float s1  = s + (p_s - e_s);                                       \
        float y   = s1 * c449; float y2 = y * y; float u = y2 * y2;        \
        float pl  = fmaf(u, fmaf(u, 0.1171875f, -0.15625f), 0.25f);        \
        s = s1 - (s1 * u) * pl;                                            \
    }

// one exact emit step (outputs p_s, perc)
#define ESTEP(dx, dy, PS, PC)                                              \
    {                                                                      \
        float pn = fmaxf((dx) - (dy), 0.0f);                               \
        float en = fmaxf((dy) - (dx), 0.0f);                               \
        float xpn = pn * inv_x1, xen = en * inv_x1;                        \
        float tp  = xpn * fmaf(xpn * xpn, -0.33333334f, 1.0f);             \
        float te  = xen * fmaf(xen * xen, -0.33333334f, 1.0f);             \
        float r   = s * inv_x1;                                            \
        float e1  = r * tp;                                                \
        float q1v = (1.0f - e1) * fmaf(e1, e1, 1.0f);                      \
        float Av  = (x1s * tp) * fmaf(-r, r, 1.0f);                        \
        float p_s = Av * q1v;                                              \
        float omr = 1.0f - r;                                              \
        float e2  = te * omr;                                              \
        float q2v = (1.0f - e2) * fmaf(e2, e2, 1.0f);                      \
        float Bv  = (s * (2.0f - r)) * te;                                 \
        float e_s = Bv * q2v;                                              \
        float s1  = s + (p_s - e_s);                                       \
        float y   = s1 * c449; float y2 = y * y; float u = y2 * y2;        \
        float pl  = fmaf(u, fmaf(u, 0.1171875f, -0.15625f), 0.25f);        \
        PC = (s1 * u) * pl;                                                \
        PS = p_s;                                                          \
        s  = s1 - PC;                                                      \
    }

#define FPAIR_R(BUF, II)                                                   \
    FSTEP(BUF.x, BUF.y, tt0 + 2 * (II))                                    \
    FSTEP(BUF.z, BUF.w, tt0 + 2 * (II) + 1)                                \
    BUF = ldx((II) + 8);
#define TGRP(B)                                                            \
    FPAIR_R(bufA, (B) + 0) FPAIR_R(bufB, (B) + 1)                          \
    FPAIR_R(bufC, (B) + 2) FPAIR_R(bufD, (B) + 3)                          \
    FPAIR_R(bufE, (B) + 4) FPAIR_R(bufF, (B) + 5)                          \
    FPAIR_R(bufG, (B) + 6) FPAIR_R(bufH, (B) + 7)

#define EPAIR(BUF, tp2)                                                    \
    {                                                                      \
        float ps0, pc0, ps1, pc1;                                          \
        ESTEP(BUF.x, BUF.y, ps0, pc0)                                      \
        ESTEP(BUF.z, BUF.w, ps1, pc1)                                      \
        if (SIDE) {                                                        \
            *(float4*)(side + 2 * (size_t)(tp2)) =                         \
                make_float4(ps0, pc0, ps1, pc1);                           \
        } else {                                                           \
            *(float2*)(out + 6 * (size_t)(tp2) + 4)  = make_float2(ps0, pc0); \
            *(float2*)(out + 6 * (size_t)(tp2) + 10) = make_float2(ps1, pc1); \
        }                                                                  \
        sum4 += ps0 + ps1; sq4 = fmaf(ps0, ps0, sq4); sq4 = fmaf(ps1, ps1, sq4); \
        sum5 += pc0 + pc1; sq5 = fmaf(pc0, pc0, sq5); sq5 = fmaf(pc1, pc1, sq5); \
    }

template <bool SIDE>
__global__ __launch_bounds__(256, 2) void scan_kernel(const float4* __restrict__ x4,
                                                      const float* __restrict__ x1p,
                                                      const float4* __restrict__ s4,
                                                      float* __restrict__ out,
                                                      float* __restrict__ side,
                                                      double* __restrict__ stats) {
    const float x1s    = x1p[0];
    const float inv_x1 = 1.0f / x1s;
    const float c449   = (4.0f / 9.0f) * inv_x1;
    const int k = blockIdx.x * 256 + threadIdx.x;      // chunk id

    // ---- coarse phase: windows k-52 .. k-13 -> padded idx k .. k+39 ----
    const float4* ps4 = s4 + k;                        // coalesced across lanes
    float4 c0 = ps4[0], c1 = ps4[1], c2 = ps4[2], c3 = ps4[3],
           c4 = ps4[4], c5 = ps4[5], c6 = ps4[6], c7 = ps4[7];
    float s = 0.0f;
    CGRP_R(0) CGRP_R(8) CGRP_R(16) CGRP_R(24) CGRP_L   // 40 coarse windows

    // ---- exact fine tail (192 steps) + emit (16 steps) ----
    const int tt0 = 16 * k - NTAIL;                    // first tail t
    auto ldx = [&](int i) -> float4 {                  // i in [0, 104)
        int idx = 8 * k - NTAIL / 2 + i;
        return x4[idx < 0 ? 0 : idx];
    };
    float4 bufA = ldx(0), bufB = ldx(1), bufC = ldx(2), bufD = ldx(3),
           bufE = ldx(4), bufF = ldx(5), bufG = ldx(6), bufH = ldx(7);
    TGRP(0)  TGRP(8)  TGRP(16) TGRP(24)
    TGRP(32) TGRP(40) TGRP(48) TGRP(56)
    TGRP(64) TGRP(72) TGRP(80) TGRP(88)                // 192 fine steps
    // (last TGRP reloads ldx(96..103) = the emit inputs)

    float sum4 = 0, sum5 = 0, sq4 = 0, sq5 = 0;
    const int t0 = 16 * k;
    EPAIR(bufA, t0 + 0)  EPAIR(bufB, t0 + 2)
    EPAIR(bufC, t0 + 4)  EPAIR(bufD, t0 + 6)
    EPAIR(bufE, t0 + 8)  EPAIR(bufF, t0 + 10)
    EPAIR(bufG, t0 + 12) EPAIR(bufH, t0 + 14)

    __shared__ double red[4][4];
    double vv[4] = {sum4, sum5, sq4, sq5};
    const int wid = threadIdx.x >> 6, lane = threadIdx.x & 63;
#pragma unroll
    for (int c = 0; c < 4; ++c) {
        double val = vv[c];
        for (int off = 32; off > 0; off >>= 1) val += __shfl_down(val, off, 64);
        if (lane == 0) red[wid][c] = val;
    }
    __syncthreads();
    if (threadIdx.x < 4) {
        int c = threadIdx.x;
        double tot = red[0][c] + red[1][c] + red[2][c] + red[3][c];
        const int ch[4] = {4, 5, 10, 11};
        atomicAdd(&stats[ch[c]], tot);
    }
}

__global__ void finalize_stats(const double* __restrict__ stats,
                               float* __restrict__ musig) {
    int c = threadIdx.x;
    if (c < 6) {
        double sum = stats[c], sumsq = stats[6 + c];
        double n = (double)T_TOTAL;
        double mu = sum / n;
        double var = (sumsq - sum * sum / n) / (n - 1.0);
        musig[c] = (float)mu;
        musig[6 + c] = (float)(1.0 / sqrt(var));
    }
}

template <bool SIDE>
__global__ __launch_bounds__(256) void normalize_kernel(const float4* __restrict__ xp4,
                                                        const float4* __restrict__ side4,
                                                        float* __restrict__ out,
                                                        const float* __restrict__ musig) {
    float mu[6], is[6];
#pragma unroll
    for (int c = 0; c < 6; ++c) { mu[c] = musig[c]; is[c] = musig[6 + c]; }

    int idx = blockIdx.x * blockDim.x + threadIdx.x;
    int stride = gridDim.x * blockDim.x;
    for (int p = idx; p < T_TOTAL / 2; p += stride) {
        float4 xv = xp4[p];
        float* o = out + 12 * (size_t)p;
        float4 sv;
        if (SIDE) {
            sv = side4[p];
        } else {
            float2 a = *(const float2*)(o + 4);
            float2 b = *(const float2*)(o + 10);
            sv = make_float4(a.x, a.y, b.x, b.y);
        }
        float pn0 = fmaxf(xv.x - xv.y, 0.0f), en0 = fmaxf(xv.y - xv.x, 0.0f);
        float pn1 = fmaxf(xv.z - xv.w, 0.0f), en1 = fmaxf(xv.w - xv.z, 0.0f);
        float4 o0 = {(xv.x - mu[0]) * is[0], (xv.y - mu[1]) * is[1],
                     (pn0 - mu[2]) * is[2], (en0 - mu[3]) * is[3]};
        float4 o1 = {(sv.x - mu[4]) * is[4], (sv.y - mu[5]) * is[5],
                     (xv.z - mu[0]) * is[0], (xv.w - mu[1]) * is[1]};
        float4 o2 = {(pn1 - mu[2]) * is[2], (en1 - mu[3]) * is[3],
                     (sv.z - mu[4]) * is[4], (sv.w - mu[5]) * is[5]};
        *(float4*)(o + 0) = o0;
        *(float4*)(o + 4) = o1;
        *(float4*)(o + 8) = o2;
    }
}

extern "C" void kernel_launch(void* const* d_in, const int* in_sizes, int n_in,
                              void* d_out, int out_size, void* d_ws, size_t ws_size,
                              hipStream_t stream) {
    const float4* x4 = (const float4*)d_in[0];
    const float* x1 = (const float*)d_in[1];
    float* out = (float*)d_out;
    char* ws = (char*)d_ws;
    double* stats = (double*)(ws + OFF_STATS);
    float* musig = (float*)(ws + OFF_MUSIG);
    float4* s4 = (float4*)(ws + OFF_S4);
    float* side = (float*)(ws + OFF_SIDE);

    const bool use_side = ws_size >= (size_t)OFF_SIDE + (size_t)T_TOTAL * 8;

    hipMemsetAsync(d_ws, 0, 96, stream);   // stats only
    prepass_kernel<<<NBLOCKS, THREADS, 0, stream>>>(x4, x1, s4, stats);
    if (use_side) {
        scan_kernel<true><<<NBLOCKS, THREADS, 0, stream>>>(x4, x1, s4, out, side, stats);
        finalize_stats<<<1, 64, 0, stream>>>(stats, musig);
        normalize_kernel<true><<<2048, 256, 0, stream>>>(x4, (const float4*)side, out, musig);
    } else {
        scan_kernel<false><<<NBLOCKS, THREADS, 0, stream>>>(x4, x1, s4, out, side, stats);
        finalize_stats<<<1, 64, 0, stream>>>(stats, musig);
        normalize_kernel<false><<<2048, 256, 0, stream>>>(x4, (const float4*)side, out, musig);
    }
}